// Round 11
// baseline (862.424 us; speedup 1.0000x reference)
//
#include <hip/hip_runtime.h>

constexpr int H = 128;        // hidden width
constexpr int EPB = 8192;     // edges per partition block
constexpr int BSH = 8;        // bucket shift: 256 nodes / bucket
constexpr int NSHADOW = 32;   // stats shadow copies (atomic de-contention)

typedef __attribute__((ext_vector_type(8))) __bf16 bf16x8;
typedef __attribute__((ext_vector_type(4))) float  f32x4;

__device__ __forceinline__ unsigned short f2bf(float f) {
  unsigned u = __builtin_bit_cast(unsigned, f);
  u += 0x7FFFu + ((u >> 16) & 1u);          // RNE
  return (unsigned short)(u >> 16);
}
__device__ __forceinline__ float bf2f(unsigned short b) {
  unsigned u = ((unsigned)b) << 16;
  return __builtin_bit_cast(float, u);
}
__device__ __forceinline__ unsigned pk2f(float x, float y) {
  return (unsigned)f2bf(x) | ((unsigned)f2bf(y) << 16);
}

__global__ void zero_k(float* p, int n) {
  const int i = blockIdx.x * 256 + threadIdx.x;
  if (i < n) p[i] = 0.f;
}

// ---- pack stacked-K weights [W_0;..;W_{R-1};loopW] (K x 128) into B-frags --
// frag at ((Ct*S+s)*64+lane)*8, S = K/32  (layout independent of GEMM KTILE)
__global__ __launch_bounds__(256) void prep_wcat_k(
    const float* __restrict__ Wr, const float* __restrict__ loopW,
    unsigned short* __restrict__ Bpre, int K, int segShift, int nRel)
{
  const int idx = blockIdx.x * 256 + threadIdx.x;
  const int S = K / 32;
  const int total = 8 * S * 64;
  if (idx >= total) return;
  const int lane = idx & 63;
  const int s    = (idx >> 6) % S;
  const int Ct   = idx / (S * 64);
  const int col  = Ct * 16 + (lane & 15);
  const int k0   = s * 32 + (lane >> 4) * 8;
  const int seg  = k0 >> segShift;
  const int segK = 1 << segShift;
  const int kk   = k0 & (segK - 1);
  const float* src = (seg < nRel) ? (Wr + ((size_t)seg * segK + kk) * H + col)
                                  : (loopW + (size_t)kk * H + col);
  unsigned short v[8];
#pragma unroll
  for (int j = 0; j < 8; ++j) v[j] = f2bf(src[(size_t)j * H]);
  unsigned short* dst = Bpre + (size_t)((Ct * S + s) * 64 + lane) * 8;
  *(uint4*)dst = *(uint4*)v;
}

// ---------------- partition stage A: per-bucket totals ----------------------
__global__ __launch_bounds__(256) void bucket_hist_k(
    const int* __restrict__ dst, int E, int* __restrict__ gcnt, int nbuckets)
{
  __shared__ int cnt[512];
  const int tid = threadIdx.x;
  for (int b = tid; b < nbuckets; b += 256) cnt[b] = 0;
  __syncthreads();
  const int base = blockIdx.x * EPB;
  for (int j = tid; j < EPB; j += 256) {
    const int e = base + j;
    if (e < E) atomicAdd(&cnt[dst[e] >> BSH], 1);
  }
  __syncthreads();
  for (int b = tid; b < nbuckets; b += 256)
    if (cnt[b]) atomicAdd(&gcnt[b], cnt[b]);
}

// ---------------- partition stage B: scan buckets, init padded cursors ------
// also zero-pads ep[E..E+7] and zeroes the dummy row N of xb/hbuf (the
// gather's zero-row target for out-of-range chunk slots)
__global__ __launch_bounds__(512) void bucket_scan_k(
    const int* __restrict__ gcnt, int* __restrict__ boffs,
    int* __restrict__ pcur, int* __restrict__ ep,
    unsigned* __restrict__ xbz, unsigned* __restrict__ hbz,
    int nbuckets, int E)
{
  __shared__ int s[512];
  const int t = threadIdx.x;
  const int x = (t < nbuckets) ? gcnt[t] : 0;
  s[t] = x; __syncthreads();
  for (int off = 1; off < 512; off <<= 1) {
    const int v = (t >= off) ? s[t - off] : 0;
    __syncthreads(); s[t] += v; __syncthreads();
  }
  if (t < nbuckets) {
    const int excl = s[t] - x;
    boffs[t] = excl;
    pcur[t * 16] = excl;          // 64B-padded cursor: own cache line
  }
  if (t == 0) boffs[nbuckets] = E;
  if (t < 8) ep[E + t] = 0;
  if (t >= 8 && t < 40)  xbz[t - 8]  = 0u;   // xb row N: 64 ushorts
  if (t >= 40 && t < 104) hbz[t - 40] = 0u;  // hbuf row N: 128 ushorts
}

// ---------------- partition stage C: block-aggregated bucket append ---------
__global__ __launch_bounds__(256) void pack2_k(
    const int* __restrict__ src, const int* __restrict__ dst,
    const int* __restrict__ et, int E,
    int* __restrict__ pcur, int* __restrict__ ep_log, int nbuckets)
{
  __shared__ int cnt[512];
  __shared__ int basel[512];
  __shared__ unsigned short ranks[EPB];
  const int tid = threadIdx.x;
  for (int b = tid; b < nbuckets; b += 256) cnt[b] = 0;
  __syncthreads();
  const int base = blockIdx.x * EPB;
  for (int j = tid; j < EPB; j += 256) {
    const int e = base + j;
    if (e < E) ranks[j] = (unsigned short)atomicAdd(&cnt[dst[e] >> BSH], 1);
  }
  __syncthreads();
  for (int b = tid; b < nbuckets; b += 256)
    basel[b] = cnt[b] ? atomicAdd(&pcur[b * 16], cnt[b]) : 0;
  __syncthreads();
  for (int j = tid; j < EPB; j += 256) {
    const int e = base + j;
    if (e < E) {
      const int d = dst[e];
      const int pos = basel[d >> BSH] + ranks[j];
      ep_log[pos] = ((d & 255) << 19) | (et[e] << 17) | src[e];
    }
  }
}

// --- partition stage D: per-bucket counting sort by (node,rel) -> ep + rowp4
// key = (local_node<<2)|etype (10 bits). Produces per-(node,relation) CSR
// ranges rowp4[node*4+r] so the gather needs no per-edge relation dispatch.
__global__ __launch_bounds__(256) void bucket_sort2_k(
    const int* __restrict__ boffs, const int* __restrict__ ep_log,
    int* __restrict__ ep, int* __restrict__ rowp4, int Nn, int E)
{
  __shared__ int ent[EPB];
  __shared__ int cntA[1024];
  __shared__ int curA[1024];
  __shared__ int tsum[256];
  const int b = blockIdx.x;
  const int tid = threadIdx.x;
  const int beg = boffs[b], end = boffs[b + 1];
  const int n = end - beg;
  const bool inl = (n <= EPB);
  if (inl) for (int i = tid; i < n; i += 256) ent[i] = ep_log[beg + i];
  for (int k = tid; k < 1024; k += 256) cntA[k] = 0;
  __syncthreads();
  for (int i = tid; i < n; i += 256) {
    const int v = inl ? ent[i] : ep_log[beg + i];
    atomicAdd(&cntA[v >> 17], 1);
  }
  __syncthreads();
  // thread t owns keys 4t..4t+3 (= local node t, relations 0..3)
  const int c0 = cntA[tid * 4], c1 = cntA[tid * 4 + 1];
  const int c2 = cntA[tid * 4 + 2], c3 = cntA[tid * 4 + 3];
  const int s1 = c0 + c1, s2 = s1 + c2;
  const int T = s2 + c3;
  tsum[tid] = T;
  __syncthreads();
  for (int off = 1; off < 256; off <<= 1) {       // inclusive scan of totals
    const int v = (tid >= off) ? tsum[tid - off] : 0;
    __syncthreads(); tsum[tid] += v; __syncthreads();
  }
  const int eb = tsum[tid] - T;                   // exclusive base for node t
  curA[tid * 4]     = eb;
  curA[tid * 4 + 1] = eb + c0;
  curA[tid * 4 + 2] = eb + s1;
  curA[tid * 4 + 3] = eb + s2;
  const int node = (b << BSH) + tid;
  if (node < Nn) {
    rowp4[node * 4]     = beg + eb;
    rowp4[node * 4 + 1] = beg + eb + c0;
    rowp4[node * 4 + 2] = beg + eb + s1;
    rowp4[node * 4 + 3] = beg + eb + s2;
  }
  if (b == 0 && tid == 0) rowp4[(size_t)Nn * 4] = E;
  __syncthreads();
  for (int i = tid; i < n; i += 256) {
    const int v = inl ? ent[i] : ep_log[beg + i];
    const int p = atomicAdd(&curA[v >> 17], 1);
    ep[beg + p] = v & 0x1FFFF;                    // src only
  }
}

// ---------------------------- x -> bf16 -------------------------------------
__global__ __launch_bounds__(256) void cvt_x_k(
    const float* __restrict__ x, unsigned short* __restrict__ xb, int nchunks)
{
  const int i = blockIdx.x * 256 + threadIdx.x;
  if (i >= nchunks) return;
  const float4 v = ((const float4*)x)[i];
  unsigned short o[4] = { f2bf(v.x), f2bf(v.y), f2bf(v.z), f2bf(v.w) };
  *(uint2*)(xb + (size_t)i * 4) = *(uint2*)o;
}

// ---- gather-then-transform: per-node per-relation sums of raw h rows -------
// CONVERGED (r6/r10 both ~73-74us, identical FETCH): memory-system-bound.
// 4-slot chunks + zero-row redirect for OOR slots (scalar s_cselect).
// Lessons: no LDS atomics (r7, 17x), no per-slot branches (r8), no extra
// live state (r9, occupancy loss).
template<int DCOLS>   // 64 (layer 0, x) or 128 (hidden, h)
__global__ __launch_bounds__(256) void gather4_k(
    const unsigned short* __restrict__ hsrc,   // [Nn+1][DCOLS], row Nn = 0
    const int* __restrict__ rowp4, const int* __restrict__ ep,
    unsigned short* __restrict__ aggcat,       // [N][4*DCOLS] bf16
    int Nn)
{
  const int tid = threadIdx.x;
  const int wave = tid >> 6, lane = tid & 63;
  const int waveId = blockIdx.x * 4 + wave;
  const int nWaves = gridDim.x * 4;
  for (int node = waveId; node < Nn; node += nWaves) {
    const int rs0 = __builtin_amdgcn_readfirstlane(rowp4[node * 4 + 0]);
    const int rs1 = __builtin_amdgcn_readfirstlane(rowp4[node * 4 + 1]);
    const int rs2 = __builtin_amdgcn_readfirstlane(rowp4[node * 4 + 2]);
    const int rs3 = __builtin_amdgcn_readfirstlane(rowp4[node * 4 + 3]);
    const int rs4 = __builtin_amdgcn_readfirstlane(rowp4[node * 4 + 4]);
    const int deg = rs4 - rs0;

    float ax[4] = {0.f, 0.f, 0.f, 0.f};
    float ay[4] = {0.f, 0.f, 0.f, 0.f};

    if (deg > 0 && deg <= 64) {
      // ---- fast path: whole edge list in one wave register ----
      const int pv = (lane < deg) ? ep[rs0 + lane] : 0;
#pragma unroll
      for (int r = 0; r < 4; ++r) {
        const int cb = (r == 0) ? 0 :
                       (r == 1) ? (rs1 - rs0) :
                       (r == 2) ? (rs2 - rs0) : (rs3 - rs0);
        const int ce = (r == 0) ? (rs1 - rs0) :
                       (r == 1) ? (rs2 - rs0) :
                       (r == 2) ? (rs3 - rs0) : deg;
        for (int t0 = cb; t0 < ce; t0 += 4) {
          const int lim = ce - 1;              // scalar
          unsigned vv[4];
#pragma unroll
          for (int j = 0; j < 4; ++j) {
            int ci = t0 + j; if (ci > lim) ci = lim;          // SALU min
            int sj = __builtin_amdgcn_readlane(pv, ci);       // SGPR
            if (t0 + j > lim) sj = Nn;                        // s_cselect
            if constexpr (DCOLS == 128)
              vv[j] = *(const unsigned*)(hsrc + (size_t)sj * DCOLS + lane * 2);
            else
              vv[j] = (unsigned)hsrc[(size_t)sj * DCOLS + lane];
          }
#pragma unroll
          for (int j = 0; j < 4; ++j) {
            if constexpr (DCOLS == 128) {
              ax[r] += __builtin_bit_cast(float, vv[j] << 16);
              ay[r] += __builtin_bit_cast(float, vv[j] & 0xFFFF0000u);
            } else {
              ax[r] += __builtin_bit_cast(float, vv[j] << 16);
            }
          }
        }
      }
    } else if (deg > 64) {
      // ---- rare path: degree > 64, per-relation 64-edge windows ----
#pragma unroll
      for (int r = 0; r < 4; ++r) {
        const int a = (r == 0) ? rs0 : (r == 1) ? rs1 : (r == 2) ? rs2 : rs3;
        const int b = (r == 0) ? rs1 : (r == 1) ? rs2 : (r == 2) ? rs3 : rs4;
        int w0 = a;
        while (w0 < b) {
          const int wlen = (b - w0) < 64 ? (b - w0) : 64;
          const int pv = (lane < wlen) ? ep[w0 + lane] : 0;
          const int lim = wlen - 1;
          for (int t0 = 0; t0 < wlen; t0 += 4) {
            unsigned vv[4];
#pragma unroll
            for (int j = 0; j < 4; ++j) {
              int ci = t0 + j; if (ci > lim) ci = lim;
              int sj = __builtin_amdgcn_readlane(pv, ci);
              if (t0 + j > lim) sj = Nn;
              if constexpr (DCOLS == 128)
                vv[j] = *(const unsigned*)(hsrc + (size_t)sj * DCOLS + lane * 2);
              else
                vv[j] = (unsigned)hsrc[(size_t)sj * DCOLS + lane];
            }
#pragma unroll
            for (int j = 0; j < 4; ++j) {
              if constexpr (DCOLS == 128) {
                ax[r] += __builtin_bit_cast(float, vv[j] << 16);
                ay[r] += __builtin_bit_cast(float, vv[j] & 0xFFFF0000u);
              } else {
                ax[r] += __builtin_bit_cast(float, vv[j] << 16);
              }
            }
          }
          w0 += wlen;
        }
      }
    }

    if constexpr (DCOLS == 128) {
      unsigned* orow = (unsigned*)(aggcat + (size_t)node * 512);
      orow[lane]       = pk2f(ax[0], ay[0]);
      orow[64  + lane] = pk2f(ax[1], ay[1]);
      orow[128 + lane] = pk2f(ax[2], ay[2]);
      orow[192 + lane] = pk2f(ax[3], ay[3]);
    } else {
      unsigned short* orow = aggcat + (size_t)node * 256;
      orow[lane]       = f2bf(ax[0]);
      orow[64  + lane] = f2bf(ax[1]);
      orow[128 + lane] = f2bf(ax[2]);
      orow[192 + lane] = f2bf(ax[3]);
    }
  }
}

// ---- concat-K GEMM, async double-buffered LDS staging, KTILE=64 ------------
// y = [A0 | A1] * Bstacked + bias. 128 rows/block, 4 waves, 2 row-tiles/wave.
// KEY FIX (r11): vmcnt is an ORDERED counter — if the A-prefetch (HBM,
// ~900cyc) is issued before the MFMA loop's B-loads, every B-wait
// transitively drains the A-loads, serializing compute behind HBM latency
// each tile. So: (1) hoist the tile's 16 B-frags into registers FIRST,
// (2) THEN issue the A-prefetch (newest in vmcnt order), (3) MFMA waits
// only vmcnt(4). sched_barrier(0) pins the B-before-A issue order.
template<int KTILE>   // 64
__global__ __launch_bounds__(256, 4) void mfma_cat_t(
    const unsigned short* __restrict__ A0, const unsigned short* __restrict__ A1,
    const unsigned short* __restrict__ Bpre, const float* __restrict__ bias,
    float* __restrict__ shadow, float* __restrict__ pre,
    int M, int W0, int D1, int nkt)
{
  constexpr int KS = KTILE / 32;
  constexpr int strideL = KTILE + 8;
  constexpr int CPR = KTILE / 8;                 // uint4 chunks per row
  constexpr int NR  = (128 * CPR) / 256;         // chunks per thread
  __shared__ unsigned short Alds[2][128 * strideL];
  __shared__ float sred[128], qred[128];
  const int tid = threadIdx.x;
  const int wave = tid >> 6, lane = tid & 63;
  const int quad = lane >> 4, l15 = lane & 15;
  const int rowBase = blockIdx.x * 128;
  const int S = nkt * KS;
  if (tid < 128) { sred[tid] = 0.f; qred[tid] = 0.f; }

  uint4 R[NR];

  auto stage_load = [&](int kt) {
    const int kbase = kt * KTILE;
    const unsigned short* base; int stride, koff;
    if (kbase < W0) { base = A0; stride = W0; koff = kbase; }
    else            { base = A1; stride = D1; koff = kbase - W0; }
#pragma unroll
    for (int i = 0; i < NR; ++i) {
      const int c = tid + i * 256;
      const int row = c / CPR, ch = c % CPR;
      const int grow = rowBase + row;
      R[i] = make_uint4(0u, 0u, 0u, 0u);
      if (grow < M)
        R[i] = *(const uint4*)(base + (size_t)grow * stride + koff + ch * 8);
    }
  };
  auto stage_write = [&](int buf) {
#pragma unroll
    for (int i = 0; i < NR; ++i) {
      const int c = tid + i * 256;
      const int row = c / CPR, ch = c % CPR;
      *(uint4*)(&Alds[buf][row * strideL + ch * 8]) = R[i];
    }
  };

  // prologue: stage tile 0
  stage_load(0);
  stage_write(0);
  __syncthreads();

  f32x4 acc[2][8] = {};
  int cur = 0;
  for (int kt = 0; kt < nkt; ++kt) {
    // 1) B frags -> registers (oldest in vmcnt order this tile)
    bf16x8 bfr[KS][8];
#pragma unroll
    for (int s = 0; s < KS; ++s) {
      const int sg = kt * KS + s;
#pragma unroll
      for (int ct = 0; ct < 8; ++ct)
        bfr[s][ct] = *(const bf16x8*)(Bpre + (size_t)((ct * S + sg) * 64 + lane) * 8);
    }
    __builtin_amdgcn_sched_barrier(0);           // pin: B issued before A
    // 2) A prefetch for next tile (HBM) — newest; B-waits won't drain it
    if (kt + 1 < nkt) stage_load(kt + 1);
    // 3) compute: ds_read A-frags + MFMA from registers
    __builtin_amdgcn_s_setprio(1);
#pragma unroll
    for (int s = 0; s < KS; ++s) {
      const bf16x8 a0f = *(const bf16x8*)(&Alds[cur][(wave * 32 + l15) * strideL + s * 32 + quad * 8]);
      const bf16x8 a1f = *(const bf16x8*)(&Alds[cur][(wave * 32 + 16 + l15) * strideL + s * 32 + quad * 8]);
#pragma unroll
      for (int ct = 0; ct < 8; ++ct) {
        acc[0][ct] = __builtin_amdgcn_mfma_f32_16x16x32_bf16(a0f, bfr[s][ct], acc[0][ct], 0, 0, 0);
        acc[1][ct] = __builtin_amdgcn_mfma_f32_16x16x32_bf16(a1f, bfr[s][ct], acc[1][ct], 0, 0, 0);
      }
    }
    __builtin_amdgcn_s_setprio(0);
    if (kt + 1 < nkt) stage_write(cur ^ 1);      // waits vmcnt(0) for A here
    __syncthreads();
    cur ^= 1;
  }

  // ---- epilogue: bias add, pre-BN fp32 write, column sum/sumsq -> shadow ---
  float bia[8];
#pragma unroll
  for (int ct = 0; ct < 8; ++ct) bia[ct] = bias[ct * 16 + l15];
  float s8[8], q8[8];
#pragma unroll
  for (int ct = 0; ct < 8; ++ct) { s8[ct] = 0.f; q8[ct] = 0.f; }
#pragma unroll
  for (int rt = 0; rt < 2; ++rt) {
#pragma unroll
    for (int reg = 0; reg < 4; ++reg) {
      const int row = rowBase + wave * 32 + rt * 16 + quad * 4 + reg;
      if (row < M) {
#pragma unroll
        for (int ct = 0; ct < 8; ++ct) {
          const float v = acc[rt][ct][reg] + bia[ct];
          pre[(size_t)row * H + ct * 16 + l15] = v;
          s8[ct] += v; q8[ct] += v * v;
        }
      }
    }
  }
#pragma unroll
  for (int ct = 0; ct < 8; ++ct) {
    s8[ct] += __shfl_xor(s8[ct], 16); s8[ct] += __shfl_xor(s8[ct], 32);
    q8[ct] += __shfl_xor(q8[ct], 16); q8[ct] += __shfl_xor(q8[ct], 32);
  }
  if (quad == 0) {
#pragma unroll
    for (int ct = 0; ct < 8; ++ct) {
      atomicAdd(&sred[ct * 16 + l15], s8[ct]);
      atomicAdd(&qred[ct * 16 + l15], q8[ct]);
    }
  }
  __syncthreads();
  if (tid < 128) {
    float* sh = shadow + (size_t)(blockIdx.x & (NSHADOW - 1)) * 256;
    atomicAdd(&sh[tid], sred[tid]);
    atomicAdd(&sh[128 + tid], qred[tid]);
  }
}

// ---- reduce shadow stats -> per-col scale/shift -----------------------------
__global__ void bn_coef_k(const float* __restrict__ shadow,
                          const float* __restrict__ gamma, const float* __restrict__ beta,
                          float* __restrict__ st, float invN)
{
  const int t = threadIdx.x;            // 128 threads
  float su = 0.f, qu = 0.f;
  for (int c = 0; c < NSHADOW; ++c) { su += shadow[c * 256 + t]; qu += shadow[c * 256 + 128 + t]; }
  const float mu  = su * invN;
  const float var = qu * invN - mu * mu;
  const float s = gamma[t] * rsqrtf(var + 1e-5f);
  st[t] = s; st[128 + t] = beta[t] - s * mu;
}

// ---- apply BN (+optional ReLU): fp32 pre -> bf16 h  /  fp32 out ------------
template<int RELU>
__global__ __launch_bounds__(256) void bn_apply_t(
    const float* __restrict__ pre, const float* __restrict__ st,
    unsigned short* __restrict__ hout, float* __restrict__ fout, int nchunks)
{
  __shared__ float ss[128], tt[128];
  if (threadIdx.x < 128) { ss[threadIdx.x] = st[threadIdx.x]; tt[threadIdx.x] = st[128 + threadIdx.x]; }
  __syncthreads();
  const int i = blockIdx.x * 256 + threadIdx.x;
  if (i >= nchunks) return;
  const float4 v = ((const float4*)pre)[i];
  const int col0 = (i & 31) * 4;
  float y0 = fmaf(ss[col0 + 0], v.x, tt[col0 + 0]);
  float y1 = fmaf(ss[col0 + 1], v.y, tt[col0 + 1]);
  float y2 = fmaf(ss[col0 + 2], v.z, tt[col0 + 2]);
  float y3 = fmaf(ss[col0 + 3], v.w, tt[col0 + 3]);
  if (RELU) {
    unsigned short o[4] = { f2bf(fmaxf(y0, 0.f)), f2bf(fmaxf(y1, 0.f)),
                            f2bf(fmaxf(y2, 0.f)), f2bf(fmaxf(y3, 0.f)) };
    *(uint2*)(hout + (size_t)i * 4) = *(uint2*)o;
  } else {
    ((float4*)fout)[i] = make_float4(y0, y1, y2, y3);
  }
}

// ---------------------------------------------------------------------------
extern "C" void kernel_launch(void* const* d_in, const int* in_sizes, int n_in,
                              void* d_out, int out_size, void* d_ws, size_t ws_size,
                              hipStream_t stream)
{
  const float* x     = (const float*)d_in[0];
  const int*   src   = (const int*)d_in[1];
  const int*   dst   = (const int*)d_in[2];
  const int*   et    = (const int*)d_in[3];
  const float* W0    = (const float*)d_in[4];
  const float* loop0 = (const float*)d_in[5];
  const float* b0    = (const float*)d_in[6];
  const float* g0    = (const float*)d_in[7];
  const float* be0   = (const float*)d_in[8];
  const float* Ws    = (const float*)d_in[9];
  const float* loops = (const float*)d_in[10];
  const float* bs    = (const float*)d_in[11];
  const float* gs    = (const float*)d_in[12];
  const float* bes   = (const float*)d_in[13];
  const float* Wl    = (const float*)d_in[14];
  const float* bl    = (const float*)d_in[15];
  const float* gl    = (const float*)d_in[16];
  const float* bel   = (const float*)d_in[17];

  const int E = in_sizes[1];
  const int F_in = 64;
  const int N = in_sizes[0] / F_in;
  const int R = in_sizes[4] / (F_in * H);        // == 4 (kernels assume 4)
  const int L = in_sizes[9] / (R * H * H);
  const float invN = 1.0f / (float)N;

  float* outp = (float*)d_out;

  // ---- workspace layout ----
  char* p = (char*)d_ws;
  auto alloc = [&](size_t bytes) { char* r = p; p += (bytes + 255) & ~size_t(255); return r; };
  const int nbuckets = (N + (1 << BSH) - 1) >> BSH;
  const int shadowN = NSHADOW * 256;                         // floats per layer
  // B-frag sizes in ushorts: K=320 / K=640 / K=128
  const int c0 = 8 * (320 / 32) * 64 * 8;
  const int ch = 8 * (640 / 32) * 64 * 8;
  const int cf = 8 * (128 / 32) * 64 * 8;
  float*          pre      = (float*)alloc((size_t)N * H * 4);          // pre-BN fp32
  float*          shadow   = (float*)alloc((size_t)(L + 2) * shadowN * 4);
  float*          st       = (float*)alloc((size_t)(L + 2) * 256 * 4);
  unsigned short* aggcat   = (unsigned short*)alloc((size_t)N * 4 * H * 2);
  unsigned short* xb       = (unsigned short*)alloc((size_t)(N + 1) * F_in * 2);  // +zero row
  unsigned short* hbuf     = (unsigned short*)alloc((size_t)(N + 1) * H * 2);     // +zero row
  unsigned short* Bpre_all = (unsigned short*)alloc((size_t)(c0 + L * ch + cf) * 2);
  int*            gcnt     = (int*)alloc((size_t)nbuckets * 4);
  int*            boffs    = (int*)alloc((size_t)(nbuckets + 1) * 4);
  int*            pcur     = (int*)alloc((size_t)nbuckets * 16 * 4);
  int*            rowp4    = (int*)alloc(((size_t)N * 4 + 1) * 4);
  int*            ep       = (int*)alloc(((size_t)E + 8) * 4);
  int*            ep_log   = (int*)pre;          // alias: only live pre-GEMM0
  (void)ws_size;

  const int pblocks = (E + EPB - 1) / EPB;
  const int rowBlocks = (N + 127) / 128;

  // ---- prepack all weights (stacked-K, bf16 B-fragment layout) ----
  hipLaunchKernelGGL(prep_wcat_k, dim3((8 * 10 * 64 + 255) / 256), dim3(256), 0, stream,
                     W0, loop0, Bpre_all, 320, 6, R);
  for (int l = 0; l < L; ++l)
    hipLaunchKernelGGL(prep_wcat_k, dim3((8 * 20 * 64 + 255) / 256), dim3(256), 0, stream,
                       Ws + (size_t)l * R * H * H, loops + (size_t)l * H * H,
                       Bpre_all + (size_t)(c0 + l * ch), 640, 7, R);
  hipLaunchKernelGGL(prep_wcat_k, dim3((8 * 4 * 64 + 255) / 256), dim3(256), 0, stream,
                     (const float*)nullptr, Wl, Bpre_all + (size_t)(c0 + L * ch), 128, 7, 0);

  // ---- zero shadow stats + bucket counters ----
  {
    const int nz = (L + 2) * shadowN;
    hipLaunchKernelGGL(zero_k, dim3((nz + 255) / 256), dim3(256), 0, stream, shadow, nz);
  }
  hipLaunchKernelGGL(zero_k, dim3((nbuckets + 255) / 256), dim3(256), 0, stream,
                     (float*)gcnt, nbuckets);

  // ---- partition: hist -> scan -> pack -> per-bucket (node,rel) sort ----
  hipLaunchKernelGGL(bucket_hist_k, dim3(pblocks), dim3(256), 0, stream, dst, E, gcnt, nbuckets);
  hipLaunchKernelGGL(bucket_scan_k, dim3(1), dim3(512), 0, stream, gcnt, boffs, pcur, ep,
                     (unsigned*)(xb + (size_t)N * F_in),
                     (unsigned*)(hbuf + (size_t)N * H), nbuckets, E);
  hipLaunchKernelGGL(pack2_k, dim3(pblocks), dim3(256), 0, stream,
                     src, dst, et, E, pcur, ep_log, nbuckets);
  hipLaunchKernelGGL(bucket_sort2_k, dim3(nbuckets), dim3(256), 0, stream,
                     boffs, ep_log, ep, rowp4, N, E);

  // ---- x -> bf16 ----
  hipLaunchKernelGGL(cvt_x_k, dim3((N * 16 + 255) / 256), dim3(256), 0, stream,
                     x, xb, N * 16);

  const int applyBlocks = (N * 32 + 255) / 256;

  // ---- layer 0: gather raw x per relation, then concat-K GEMM ----
  hipLaunchKernelGGL((gather4_k<64>), dim3(2048), dim3(256), 0, stream,
                     xb, rowp4, ep, aggcat, N);
  hipLaunchKernelGGL((mfma_cat_t<64>), dim3(rowBlocks), dim3(256), 0, stream,
                     aggcat, xb, Bpre_all, b0, shadow, pre, N, 4 * F_in, F_in, 5);
  hipLaunchKernelGGL(bn_coef_k, dim3(1), dim3(128), 0, stream, shadow, g0, be0, st, invN);
  hipLaunchKernelGGL((bn_apply_t<1>), dim3(applyBlocks), dim3(256), 0, stream,
                     pre, st, hbuf, (float*)nullptr, N * 32);

  // ---- hidden conv layers ----
  for (int l = 0; l < L; ++l) {
    hipLaunchKernelGGL((gather4_k<128>), dim3(2048), dim3(256), 0, stream,
                       hbuf, rowp4, ep, aggcat, N);
    hipLaunchKernelGGL((mfma_cat_t<64>), dim3(rowBlocks), dim3(256), 0, stream,
                       aggcat, hbuf, Bpre_all + (size_t)(c0 + l * ch), bs + (size_t)l * H,
                       shadow + (size_t)(1 + l) * shadowN, pre, N, 4 * H, H, 10);
    hipLaunchKernelGGL(bn_coef_k, dim3(1), dim3(128), 0, stream,
                       shadow + (size_t)(1 + l) * shadowN, gs + (size_t)l * H, bes + (size_t)l * H,
                       st + (size_t)(1 + l) * 256, invN);
    hipLaunchKernelGGL((bn_apply_t<1>), dim3(applyBlocks), dim3(256), 0, stream,
                       pre, st + (size_t)(1 + l) * 256, hbuf, (float*)nullptr, N * 32);
  }

  // ---- final linear + BN (no ReLU) -> d_out ----
  hipLaunchKernelGGL((mfma_cat_t<64>), dim3(rowBlocks), dim3(256), 0, stream,
                     (const unsigned short*)nullptr, hbuf, Bpre_all + (size_t)(c0 + L * ch), bl,
                     shadow + (size_t)(1 + L) * shadowN, pre, N, 0, H, 2);
  hipLaunchKernelGGL(bn_coef_k, dim3(1), dim3(128), 0, stream,
                     shadow + (size_t)(1 + L) * shadowN, gl, bel,
                     st + (size_t)(1 + L) * 256, invN);
  hipLaunchKernelGGL((bn_apply_t<0>), dim3(applyBlocks), dim3(256), 0, stream,
                     pre, st + (size_t)(1 + L) * 256, (unsigned short*)nullptr, outp, N * 32);
}

// Round 12
// 650.238 us; speedup vs baseline: 1.3263x; 1.3263x over previous
//
#include <hip/hip_runtime.h>

constexpr int H = 128;        // hidden width
constexpr int EPB = 8192;     // edges per partition block
constexpr int BSH = 8;        // bucket shift: 256 nodes / bucket
constexpr int NSHADOW = 32;   // stats shadow copies (atomic de-contention)

typedef __attribute__((ext_vector_type(8))) __bf16 bf16x8;
typedef __attribute__((ext_vector_type(4))) float  f32x4;

__device__ __forceinline__ unsigned short f2bf(float f) {
  unsigned u = __builtin_bit_cast(unsigned, f);
  u += 0x7FFFu + ((u >> 16) & 1u);          // RNE
  return (unsigned short)(u >> 16);
}
__device__ __forceinline__ float bf2f(unsigned short b) {
  unsigned u = ((unsigned)b) << 16;
  return __builtin_bit_cast(float, u);
}
__device__ __forceinline__ unsigned pk2f(float x, float y) {
  return (unsigned)f2bf(x) | ((unsigned)f2bf(y) << 16);
}

__global__ void zero_k(float* p, int n) {
  const int i = blockIdx.x * 256 + threadIdx.x;
  if (i < n) p[i] = 0.f;
}

// ---- pack stacked-K weights [W_0;..;W_{R-1};loopW] (K x 128) into B-frags --
// frag at ((Ct*S+s)*64+lane)*8, S = K/32  (layout independent of GEMM KTILE)
__global__ __launch_bounds__(256) void prep_wcat_k(
    const float* __restrict__ Wr, const float* __restrict__ loopW,
    unsigned short* __restrict__ Bpre, int K, int segShift, int nRel)
{
  const int idx = blockIdx.x * 256 + threadIdx.x;
  const int S = K / 32;
  const int total = 8 * S * 64;
  if (idx >= total) return;
  const int lane = idx & 63;
  const int s    = (idx >> 6) % S;
  const int Ct   = idx / (S * 64);
  const int col  = Ct * 16 + (lane & 15);
  const int k0   = s * 32 + (lane >> 4) * 8;
  const int seg  = k0 >> segShift;
  const int segK = 1 << segShift;
  const int kk   = k0 & (segK - 1);
  const float* src = (seg < nRel) ? (Wr + ((size_t)seg * segK + kk) * H + col)
                                  : (loopW + (size_t)kk * H + col);
  unsigned short v[8];
#pragma unroll
  for (int j = 0; j < 8; ++j) v[j] = f2bf(src[(size_t)j * H]);
  unsigned short* dst = Bpre + (size_t)((Ct * S + s) * 64 + lane) * 8;
  *(uint4*)dst = *(uint4*)v;
}

// ---------------- partition stage A: per-bucket totals ----------------------
__global__ __launch_bounds__(256) void bucket_hist_k(
    const int* __restrict__ dst, int E, int* __restrict__ gcnt, int nbuckets)
{
  __shared__ int cnt[512];
  const int tid = threadIdx.x;
  for (int b = tid; b < nbuckets; b += 256) cnt[b] = 0;
  __syncthreads();
  const int base = blockIdx.x * EPB;
  for (int j = tid; j < EPB; j += 256) {
    const int e = base + j;
    if (e < E) atomicAdd(&cnt[dst[e] >> BSH], 1);
  }
  __syncthreads();
  for (int b = tid; b < nbuckets; b += 256)
    if (cnt[b]) atomicAdd(&gcnt[b], cnt[b]);
}

// ---------------- partition stage B: scan buckets, init padded cursors ------
// also zero-pads ep[E..E+7] and zeroes the dummy row N of xb/hbuf (the
// gather's zero-row target for out-of-range chunk slots)
__global__ __launch_bounds__(512) void bucket_scan_k(
    const int* __restrict__ gcnt, int* __restrict__ boffs,
    int* __restrict__ pcur, int* __restrict__ ep,
    unsigned* __restrict__ xbz, unsigned* __restrict__ hbz,
    int nbuckets, int E)
{
  __shared__ int s[512];
  const int t = threadIdx.x;
  const int x = (t < nbuckets) ? gcnt[t] : 0;
  s[t] = x; __syncthreads();
  for (int off = 1; off < 512; off <<= 1) {
    const int v = (t >= off) ? s[t - off] : 0;
    __syncthreads(); s[t] += v; __syncthreads();
  }
  if (t < nbuckets) {
    const int excl = s[t] - x;
    boffs[t] = excl;
    pcur[t * 16] = excl;          // 64B-padded cursor: own cache line
  }
  if (t == 0) boffs[nbuckets] = E;
  if (t < 8) ep[E + t] = 0;
  if (t >= 8 && t < 40)  xbz[t - 8]  = 0u;   // xb row N: 64 ushorts
  if (t >= 40 && t < 104) hbz[t - 40] = 0u;  // hbuf row N: 128 ushorts
}

// ---------------- partition stage C: block-aggregated bucket append ---------
__global__ __launch_bounds__(256) void pack2_k(
    const int* __restrict__ src, const int* __restrict__ dst,
    const int* __restrict__ et, int E,
    int* __restrict__ pcur, int* __restrict__ ep_log, int nbuckets)
{
  __shared__ int cnt[512];
  __shared__ int basel[512];
  __shared__ unsigned short ranks[EPB];
  const int tid = threadIdx.x;
  for (int b = tid; b < nbuckets; b += 256) cnt[b] = 0;
  __syncthreads();
  const int base = blockIdx.x * EPB;
  for (int j = tid; j < EPB; j += 256) {
    const int e = base + j;
    if (e < E) ranks[j] = (unsigned short)atomicAdd(&cnt[dst[e] >> BSH], 1);
  }
  __syncthreads();
  for (int b = tid; b < nbuckets; b += 256)
    basel[b] = cnt[b] ? atomicAdd(&pcur[b * 16], cnt[b]) : 0;
  __syncthreads();
  for (int j = tid; j < EPB; j += 256) {
    const int e = base + j;
    if (e < E) {
      const int d = dst[e];
      const int pos = basel[d >> BSH] + ranks[j];
      ep_log[pos] = ((d & 255) << 19) | (et[e] << 17) | src[e];
    }
  }
}

// --- partition stage D: per-bucket counting sort by (node,rel) -> ep + rowp4
// key = (local_node<<2)|etype (10 bits). Produces per-(node,relation) CSR
// ranges rowp4[node*4+r] so the gather needs no per-edge relation dispatch.
__global__ __launch_bounds__(256) void bucket_sort2_k(
    const int* __restrict__ boffs, const int* __restrict__ ep_log,
    int* __restrict__ ep, int* __restrict__ rowp4, int Nn, int E)
{
  __shared__ int ent[EPB];
  __shared__ int cntA[1024];
  __shared__ int curA[1024];
  __shared__ int tsum[256];
  const int b = blockIdx.x;
  const int tid = threadIdx.x;
  const int beg = boffs[b], end = boffs[b + 1];
  const int n = end - beg;
  const bool inl = (n <= EPB);
  if (inl) for (int i = tid; i < n; i += 256) ent[i] = ep_log[beg + i];
  for (int k = tid; k < 1024; k += 256) cntA[k] = 0;
  __syncthreads();
  for (int i = tid; i < n; i += 256) {
    const int v = inl ? ent[i] : ep_log[beg + i];
    atomicAdd(&cntA[v >> 17], 1);
  }
  __syncthreads();
  // thread t owns keys 4t..4t+3 (= local node t, relations 0..3)
  const int c0 = cntA[tid * 4], c1 = cntA[tid * 4 + 1];
  const int c2 = cntA[tid * 4 + 2], c3 = cntA[tid * 4 + 3];
  const int s1 = c0 + c1, s2 = s1 + c2;
  const int T = s2 + c3;
  tsum[tid] = T;
  __syncthreads();
  for (int off = 1; off < 256; off <<= 1) {       // inclusive scan of totals
    const int v = (tid >= off) ? tsum[tid - off] : 0;
    __syncthreads(); tsum[tid] += v; __syncthreads();
  }
  const int eb = tsum[tid] - T;                   // exclusive base for node t
  curA[tid * 4]     = eb;
  curA[tid * 4 + 1] = eb + c0;
  curA[tid * 4 + 2] = eb + s1;
  curA[tid * 4 + 3] = eb + s2;
  const int node = (b << BSH) + tid;
  if (node < Nn) {
    rowp4[node * 4]     = beg + eb;
    rowp4[node * 4 + 1] = beg + eb + c0;
    rowp4[node * 4 + 2] = beg + eb + s1;
    rowp4[node * 4 + 3] = beg + eb + s2;
  }
  if (b == 0 && tid == 0) rowp4[(size_t)Nn * 4] = E;
  __syncthreads();
  for (int i = tid; i < n; i += 256) {
    const int v = inl ? ent[i] : ep_log[beg + i];
    const int p = atomicAdd(&curA[v >> 17], 1);
    ep[beg + p] = v & 0x1FFFF;                    // src only
  }
}

// ---------------------------- x -> bf16 -------------------------------------
__global__ __launch_bounds__(256) void cvt_x_k(
    const float* __restrict__ x, unsigned short* __restrict__ xb, int nchunks)
{
  const int i = blockIdx.x * 256 + threadIdx.x;
  if (i >= nchunks) return;
  const float4 v = ((const float4*)x)[i];
  unsigned short o[4] = { f2bf(v.x), f2bf(v.y), f2bf(v.z), f2bf(v.w) };
  *(uint2*)(xb + (size_t)i * 4) = *(uint2*)o;
}

// ---- gather-then-transform: per-node per-relation sums of raw h rows -------
// CONVERGED (r6/r10 both ~73-74us, identical FETCH): memory-system-bound.
// 4-slot chunks + zero-row redirect for OOR slots (scalar s_cselect).
// Lessons: no LDS atomics (r7, 17x), no per-slot branches (r8), no extra
// live state (r9, occupancy loss).
template<int DCOLS>   // 64 (layer 0, x) or 128 (hidden, h)
__global__ __launch_bounds__(256) void gather4_k(
    const unsigned short* __restrict__ hsrc,   // [Nn+1][DCOLS], row Nn = 0
    const int* __restrict__ rowp4, const int* __restrict__ ep,
    unsigned short* __restrict__ aggcat,       // [N][4*DCOLS] bf16
    int Nn)
{
  const int tid = threadIdx.x;
  const int wave = tid >> 6, lane = tid & 63;
  const int waveId = blockIdx.x * 4 + wave;
  const int nWaves = gridDim.x * 4;
  for (int node = waveId; node < Nn; node += nWaves) {
    const int rs0 = __builtin_amdgcn_readfirstlane(rowp4[node * 4 + 0]);
    const int rs1 = __builtin_amdgcn_readfirstlane(rowp4[node * 4 + 1]);
    const int rs2 = __builtin_amdgcn_readfirstlane(rowp4[node * 4 + 2]);
    const int rs3 = __builtin_amdgcn_readfirstlane(rowp4[node * 4 + 3]);
    const int rs4 = __builtin_amdgcn_readfirstlane(rowp4[node * 4 + 4]);
    const int deg = rs4 - rs0;

    float ax[4] = {0.f, 0.f, 0.f, 0.f};
    float ay[4] = {0.f, 0.f, 0.f, 0.f};

    if (deg > 0 && deg <= 64) {
      // ---- fast path: whole edge list in one wave register ----
      const int pv = (lane < deg) ? ep[rs0 + lane] : 0;
#pragma unroll
      for (int r = 0; r < 4; ++r) {
        const int cb = (r == 0) ? 0 :
                       (r == 1) ? (rs1 - rs0) :
                       (r == 2) ? (rs2 - rs0) : (rs3 - rs0);
        const int ce = (r == 0) ? (rs1 - rs0) :
                       (r == 1) ? (rs2 - rs0) :
                       (r == 2) ? (rs3 - rs0) : deg;
        for (int t0 = cb; t0 < ce; t0 += 4) {
          const int lim = ce - 1;              // scalar
          unsigned vv[4];
#pragma unroll
          for (int j = 0; j < 4; ++j) {
            int ci = t0 + j; if (ci > lim) ci = lim;          // SALU min
            int sj = __builtin_amdgcn_readlane(pv, ci);       // SGPR
            if (t0 + j > lim) sj = Nn;                        // s_cselect
            if constexpr (DCOLS == 128)
              vv[j] = *(const unsigned*)(hsrc + (size_t)sj * DCOLS + lane * 2);
            else
              vv[j] = (unsigned)hsrc[(size_t)sj * DCOLS + lane];
          }
#pragma unroll
          for (int j = 0; j < 4; ++j) {
            if constexpr (DCOLS == 128) {
              ax[r] += __builtin_bit_cast(float, vv[j] << 16);
              ay[r] += __builtin_bit_cast(float, vv[j] & 0xFFFF0000u);
            } else {
              ax[r] += __builtin_bit_cast(float, vv[j] << 16);
            }
          }
        }
      }
    } else if (deg > 64) {
      // ---- rare path: degree > 64, per-relation 64-edge windows ----
#pragma unroll
      for (int r = 0; r < 4; ++r) {
        const int a = (r == 0) ? rs0 : (r == 1) ? rs1 : (r == 2) ? rs2 : rs3;
        const int b = (r == 0) ? rs1 : (r == 1) ? rs2 : (r == 2) ? rs3 : rs4;
        int w0 = a;
        while (w0 < b) {
          const int wlen = (b - w0) < 64 ? (b - w0) : 64;
          const int pv = (lane < wlen) ? ep[w0 + lane] : 0;
          const int lim = wlen - 1;
          for (int t0 = 0; t0 < wlen; t0 += 4) {
            unsigned vv[4];
#pragma unroll
            for (int j = 0; j < 4; ++j) {
              int ci = t0 + j; if (ci > lim) ci = lim;
              int sj = __builtin_amdgcn_readlane(pv, ci);
              if (t0 + j > lim) sj = Nn;
              if constexpr (DCOLS == 128)
                vv[j] = *(const unsigned*)(hsrc + (size_t)sj * DCOLS + lane * 2);
              else
                vv[j] = (unsigned)hsrc[(size_t)sj * DCOLS + lane];
            }
#pragma unroll
            for (int j = 0; j < 4; ++j) {
              if constexpr (DCOLS == 128) {
                ax[r] += __builtin_bit_cast(float, vv[j] << 16);
                ay[r] += __builtin_bit_cast(float, vv[j] & 0xFFFF0000u);
              } else {
                ax[r] += __builtin_bit_cast(float, vv[j] << 16);
              }
            }
          }
          w0 += wlen;
        }
      }
    }

    if constexpr (DCOLS == 128) {
      unsigned* orow = (unsigned*)(aggcat + (size_t)node * 512);
      orow[lane]       = pk2f(ax[0], ay[0]);
      orow[64  + lane] = pk2f(ax[1], ay[1]);
      orow[128 + lane] = pk2f(ax[2], ay[2]);
      orow[192 + lane] = pk2f(ax[3], ay[3]);
    } else {
      unsigned short* orow = aggcat + (size_t)node * 256;
      orow[lane]       = f2bf(ax[0]);
      orow[64  + lane] = f2bf(ax[1]);
      orow[128 + lane] = f2bf(ax[2]);
      orow[192 + lane] = f2bf(ax[3]);
    }
  }
}

// ---- concat-K GEMM: A AND B double-buffered in LDS (m97 pattern) -----------
// r10 diagnosis: vmcnt retires IN ISSUE ORDER, so B-uses (global loads inside
// the MFMA loop) transitively drained the older A-prefetch HBM loads every
// tile -> MfmaUtil 8%. r11 lesson: fixing this by hoisting B into registers
// across a sched_barrier SPILLS (WRITE_SIZE 51->316MB) under tight bounds.
// Correct fix: stage the B-tile in LDS too (chunk-linear frag layout, lane*16B
// -> naturally conflict-free ds_read_b128). The compute phase then runs
// entirely on lgkmcnt; vmcnt waits only at tile-end staging writes, covered
// by the compute + co-resident block. LDS 70.7KB -> 2 blocks/CU; bounds
// (256,2) -> 256-VGPR cap, no spill possible.
template<int KTILE>   // 64
__global__ __launch_bounds__(256, 2) void mfma_cat_t(
    const unsigned short* __restrict__ A0, const unsigned short* __restrict__ A1,
    const unsigned short* __restrict__ Bpre, const float* __restrict__ bias,
    float* __restrict__ shadow, float* __restrict__ pre,
    int M, int W0, int D1, int nkt)
{
  constexpr int KS = KTILE / 32;                 // 2
  constexpr int strideL = KTILE + 8;
  constexpr int CPR = KTILE / 8;                 // uint4 chunks per A row
  constexpr int NR  = (128 * CPR) / 256;         // A chunks per thread
  constexpr int NBCH = 8 * KS;                   // B chunks per tile (16)
  __shared__ unsigned short Alds[2][128 * strideL];
  __shared__ unsigned short Blds[2][NBCH * 512];
  __shared__ float sred[128], qred[128];
  const int tid = threadIdx.x;
  const int wave = tid >> 6, lane = tid & 63;
  const int quad = lane >> 4, l15 = lane & 15;
  const int rowBase = blockIdx.x * 128;
  const int S = nkt * KS;
  if (tid < 128) { sred[tid] = 0.f; qred[tid] = 0.f; }

  uint4 R[NR];
  uint4 RB[4];

  auto loadA = [&](int kt) {
    const int kbase = kt * KTILE;
    const unsigned short* base; int stride, koff;
    if (kbase < W0) { base = A0; stride = W0; koff = kbase; }
    else            { base = A1; stride = D1; koff = kbase - W0; }
#pragma unroll
    for (int i = 0; i < NR; ++i) {
      const int c = tid + i * 256;
      const int row = c / CPR, ch = c % CPR;
      const int grow = rowBase + row;
      R[i] = make_uint4(0u, 0u, 0u, 0u);
      if (grow < M)
        R[i] = *(const uint4*)(base + (size_t)grow * stride + koff + ch * 8);
    }
  };
  auto writeA = [&](int buf) {
#pragma unroll
    for (int i = 0; i < NR; ++i) {
      const int c = tid + i * 256;
      const int row = c / CPR, ch = c % CPR;
      *(uint4*)(&Alds[buf][row * strideL + ch * 8]) = R[i];
    }
  };
  auto loadB = [&](int kt) {
#pragma unroll
    for (int p = 0; p < 4; ++p) {
      const int c = wave + p * 4;                // chunk id 0..15
      const int ct = c / KS, s = c % KS;
      RB[p] = *(const uint4*)(Bpre + ((size_t)(ct * S + kt * KS + s) * 64 + lane) * 8);
    }
  };
  auto writeB = [&](int buf) {
#pragma unroll
    for (int p = 0; p < 4; ++p) {
      const int c = wave + p * 4;
      *(uint4*)(&Blds[buf][(size_t)c * 512 + lane * 8]) = RB[p];
    }
  };

  // prologue: stage tile 0 (A and B)
  loadB(0); loadA(0);
  writeB(0); writeA(0);
  __syncthreads();

  f32x4 acc[2][8] = {};
  int cur = 0;
  for (int kt = 0; kt < nkt; ++kt) {
    if (kt + 1 < nkt) { loadB(kt + 1); loadA(kt + 1); }   // issue early
    __builtin_amdgcn_sched_barrier(0);                    // pin issue point
    __builtin_amdgcn_s_setprio(1);
#pragma unroll
    for (int s = 0; s < KS; ++s) {
      const bf16x8 a0f = *(const bf16x8*)(&Alds[cur][(wave * 32 + l15) * strideL + s * 32 + quad * 8]);
      const bf16x8 a1f = *(const bf16x8*)(&Alds[cur][(wave * 32 + 16 + l15) * strideL + s * 32 + quad * 8]);
#pragma unroll
      for (int ct = 0; ct < 8; ++ct) {
        const bf16x8 b = *(const bf16x8*)(&Blds[cur][(ct * KS + s) * 512 + lane * 8]);
        acc[0][ct] = __builtin_amdgcn_mfma_f32_16x16x32_bf16(a0f, b, acc[0][ct], 0, 0, 0);
        acc[1][ct] = __builtin_amdgcn_mfma_f32_16x16x32_bf16(a1f, b, acc[1][ct], 0, 0, 0);
      }
    }
    __builtin_amdgcn_s_setprio(0);
    __builtin_amdgcn_sched_barrier(0);
    if (kt + 1 < nkt) { writeB(cur ^ 1); writeA(cur ^ 1); }  // vmcnt waits here
    __syncthreads();
    cur ^= 1;
  }

  // ---- epilogue: bias add, pre-BN fp32 write, column sum/sumsq -> shadow ---
  float bia[8];
#pragma unroll
  for (int ct = 0; ct < 8; ++ct) bia[ct] = bias[ct * 16 + l15];
  float s8[8], q8[8];
#pragma unroll
  for (int ct = 0; ct < 8; ++ct) { s8[ct] = 0.f; q8[ct] = 0.f; }
#pragma unroll
  for (int rt = 0; rt < 2; ++rt) {
#pragma unroll
    for (int reg = 0; reg < 4; ++reg) {
      const int row = rowBase + wave * 32 + rt * 16 + quad * 4 + reg;
      if (row < M) {
#pragma unroll
        for (int ct = 0; ct < 8; ++ct) {
          const float v = acc[rt][ct][reg] + bia[ct];
          pre[(size_t)row * H + ct * 16 + l15] = v;
          s8[ct] += v; q8[ct] += v * v;
        }
      }
    }
  }
#pragma unroll
  for (int ct = 0; ct < 8; ++ct) {
    s8[ct] += __shfl_xor(s8[ct], 16); s8[ct] += __shfl_xor(s8[ct], 32);
    q8[ct] += __shfl_xor(q8[ct], 16); q8[ct] += __shfl_xor(q8[ct], 32);
  }
  if (quad == 0) {
#pragma unroll
    for (int ct = 0; ct < 8; ++ct) {
      atomicAdd(&sred[ct * 16 + l15], s8[ct]);
      atomicAdd(&qred[ct * 16 + l15], q8[ct]);
    }
  }
  __syncthreads();
  if (tid < 128) {
    float* sh = shadow + (size_t)(blockIdx.x & (NSHADOW - 1)) * 256;
    atomicAdd(&sh[tid], sred[tid]);
    atomicAdd(&sh[128 + tid], qred[tid]);
  }
}

// ---- reduce shadow stats -> per-col scale/shift -----------------------------
__global__ void bn_coef_k(const float* __restrict__ shadow,
                          const float* __restrict__ gamma, const float* __restrict__ beta,
                          float* __restrict__ st, float invN)
{
  const int t = threadIdx.x;            // 128 threads
  float su = 0.f, qu = 0.f;
  for (int c = 0; c < NSHADOW; ++c) { su += shadow[c * 256 + t]; qu += shadow[c * 256 + 128 + t]; }
  const float mu  = su * invN;
  const float var = qu * invN - mu * mu;
  const float s = gamma[t] * rsqrtf(var + 1e-5f);
  st[t] = s; st[128 + t] = beta[t] - s * mu;
}

// ---- apply BN (+optional ReLU): fp32 pre -> bf16 h  /  fp32 out ------------
template<int RELU>
__global__ __launch_bounds__(256) void bn_apply_t(
    const float* __restrict__ pre, const float* __restrict__ st,
    unsigned short* __restrict__ hout, float* __restrict__ fout, int nchunks)
{
  __shared__ float ss[128], tt[128];
  if (threadIdx.x < 128) { ss[threadIdx.x] = st[threadIdx.x]; tt[threadIdx.x] = st[128 + threadIdx.x]; }
  __syncthreads();
  const int i = blockIdx.x * 256 + threadIdx.x;
  if (i >= nchunks) return;
  const float4 v = ((const float4*)pre)[i];
  const int col0 = (i & 31) * 4;
  float y0 = fmaf(ss[col0 + 0], v.x, tt[col0 + 0]);
  float y1 = fmaf(ss[col0 + 1], v.y, tt[col0 + 1]);
  float y2 = fmaf(ss[col0 + 2], v.z, tt[col0 + 2]);
  float y3 = fmaf(ss[col0 + 3], v.w, tt[col0 + 3]);
  if (RELU) {
    unsigned short o[4] = { f2bf(fmaxf(y0, 0.f)), f2bf(fmaxf(y1, 0.f)),
                            f2bf(fmaxf(y2, 0.f)), f2bf(fmaxf(y3, 0.f)) };
    *(uint2*)(hout + (size_t)i * 4) = *(uint2*)o;
  } else {
    ((float4*)fout)[i] = make_float4(y0, y1, y2, y3);
  }
}

// ---------------------------------------------------------------------------
extern "C" void kernel_launch(void* const* d_in, const int* in_sizes, int n_in,
                              void* d_out, int out_size, void* d_ws, size_t ws_size,
                              hipStream_t stream)
{
  const float* x     = (const float*)d_in[0];
  const int*   src   = (const int*)d_in[1];
  const int*   dst   = (const int*)d_in[2];
  const int*   et    = (const int*)d_in[3];
  const float* W0    = (const float*)d_in[4];
  const float* loop0 = (const float*)d_in[5];
  const float* b0    = (const float*)d_in[6];
  const float* g0    = (const float*)d_in[7];
  const float* be0   = (const float*)d_in[8];
  const float* Ws    = (const float*)d_in[9];
  const float* loops = (const float*)d_in[10];
  const float* bs    = (const float*)d_in[11];
  const float* gs    = (const float*)d_in[12];
  const float* bes   = (const float*)d_in[13];
  const float* Wl    = (const float*)d_in[14];
  const float* bl    = (const float*)d_in[15];
  const float* gl    = (const float*)d_in[16];
  const float* bel   = (const float*)d_in[17];

  const int E = in_sizes[1];
  const int F_in = 64;
  const int N = in_sizes[0] / F_in;
  const int R = in_sizes[4] / (F_in * H);        // == 4 (kernels assume 4)
  const int L = in_sizes[9] / (R * H * H);
  const float invN = 1.0f / (float)N;

  float* outp = (float*)d_out;

  // ---- workspace layout ----
  char* p = (char*)d_ws;
  auto alloc = [&](size_t bytes) { char* r = p; p += (bytes + 255) & ~size_t(255); return r; };
  const int nbuckets = (N + (1 << BSH) - 1) >> BSH;
  const int shadowN = NSHADOW * 256;                         // floats per layer
  // B-frag sizes in ushorts: K=320 / K=640 / K=128
  const int c0 = 8 * (320 / 32) * 64 * 8;
  const int ch = 8 * (640 / 32) * 64 * 8;
  const int cf = 8 * (128 / 32) * 64 * 8;
  float*          pre      = (float*)alloc((size_t)N * H * 4);          // pre-BN fp32
  float*          shadow   = (float*)alloc((size_t)(L + 2) * shadowN * 4);
  float*          st       = (float*)alloc((size_t)(L + 2) * 256 * 4);
  unsigned short* aggcat   = (unsigned short*)alloc((size_t)N * 4 * H * 2);
  unsigned short* xb       = (unsigned short*)alloc((size_t)(N + 1) * F_in * 2);  // +zero row
  unsigned short* hbuf     = (unsigned short*)alloc((size_t)(N + 1) * H * 2);     // +zero row
  unsigned short* Bpre_all = (unsigned short*)alloc((size_t)(c0 + L * ch + cf) * 2);
  int*            gcnt     = (int*)alloc((size_t)nbuckets * 4);
  int*            boffs    = (int*)alloc((size_t)(nbuckets + 1) * 4);
  int*            pcur     = (int*)alloc((size_t)nbuckets * 16 * 4);
  int*            rowp4    = (int*)alloc(((size_t)N * 4 + 1) * 4);
  int*            ep       = (int*)alloc(((size_t)E + 8) * 4);
  int*            ep_log   = (int*)pre;          // alias: only live pre-GEMM0
  (void)ws_size;

  const int pblocks = (E + EPB - 1) / EPB;
  const int rowBlocks = (N + 127) / 128;

  // ---- prepack all weights (stacked-K, bf16 B-fragment layout) ----
  hipLaunchKernelGGL(prep_wcat_k, dim3((8 * 10 * 64 + 255) / 256), dim3(256), 0, stream,
                     W0, loop0, Bpre_all, 320, 6, R);
  for (int l = 0; l < L; ++l)
    hipLaunchKernelGGL(prep_wcat_k, dim3((8 * 20 * 64 + 255) / 256), dim3(256), 0, stream,
                       Ws + (size_t)l * R * H * H, loops + (size_t)l * H * H,
                       Bpre_all + (size_t)(c0 + l * ch), 640, 7, R);
  hipLaunchKernelGGL(prep_wcat_k, dim3((8 * 4 * 64 + 255) / 256), dim3(256), 0, stream,
                     (const float*)nullptr, Wl, Bpre_all + (size_t)(c0 + L * ch), 128, 7, 0);

  // ---- zero shadow stats + bucket counters ----
  {
    const int nz = (L + 2) * shadowN;
    hipLaunchKernelGGL(zero_k, dim3((nz + 255) / 256), dim3(256), 0, stream, shadow, nz);
  }
  hipLaunchKernelGGL(zero_k, dim3((nbuckets + 255) / 256), dim3(256), 0, stream,
                     (float*)gcnt, nbuckets);

  // ---- partition: hist -> scan -> pack -> per-bucket (node,rel) sort ----
  hipLaunchKernelGGL(bucket_hist_k, dim3(pblocks), dim3(256), 0, stream, dst, E, gcnt, nbuckets);
  hipLaunchKernelGGL(bucket_scan_k, dim3(1), dim3(512), 0, stream, gcnt, boffs, pcur, ep,
                     (unsigned*)(xb + (size_t)N * F_in),
                     (unsigned*)(hbuf + (size_t)N * H), nbuckets, E);
  hipLaunchKernelGGL(pack2_k, dim3(pblocks), dim3(256), 0, stream,
                     src, dst, et, E, pcur, ep_log, nbuckets);
  hipLaunchKernelGGL(bucket_sort2_k, dim3(nbuckets), dim3(256), 0, stream,
                     boffs, ep_log, ep, rowp4, N, E);

  // ---- x -> bf16 ----
  hipLaunchKernelGGL(cvt_x_k, dim3((N * 16 + 255) / 256), dim3(256), 0, stream,
                     x, xb, N * 16);

  const int applyBlocks = (N * 32 + 255) / 256;

  // ---- layer 0: gather raw x per relation, then concat-K GEMM ----
  hipLaunchKernelGGL((gather4_k<64>), dim3(2048), dim3(256), 0, stream,
                     xb, rowp4, ep, aggcat, N);
  hipLaunchKernelGGL((mfma_cat_t<64>), dim3(rowBlocks), dim3(256), 0, stream,
                     aggcat, xb, Bpre_all, b0, shadow, pre, N, 4 * F_in, F_in, 5);
  hipLaunchKernelGGL(bn_coef_k, dim3(1), dim3(128), 0, stream, shadow, g0, be0, st, invN);
  hipLaunchKernelGGL((bn_apply_t<1>), dim3(applyBlocks), dim3(256), 0, stream,
                     pre, st, hbuf, (float*)nullptr, N * 32);

  // ---- hidden conv layers ----
  for (int l = 0; l < L; ++l) {
    hipLaunchKernelGGL((gather4_k<128>), dim3(2048), dim3(256), 0, stream,
                       hbuf, rowp4, ep, aggcat, N);
    hipLaunchKernelGGL((mfma_cat_t<64>), dim3(rowBlocks), dim3(256), 0, stream,
                       aggcat, hbuf, Bpre_all + (size_t)(c0 + l * ch), bs + (size_t)l * H,
                       shadow + (size_t)(1 + l) * shadowN, pre, N, 4 * H, H, 10);
    hipLaunchKernelGGL(bn_coef_k, dim3(1), dim3(128), 0, stream,
                       shadow + (size_t)(1 + l) * shadowN, gs + (size_t)l * H, bes + (size_t)l * H,
                       st + (size_t)(1 + l) * 256, invN);
    hipLaunchKernelGGL((bn_apply_t<1>), dim3(applyBlocks), dim3(256), 0, stream,
                       pre, st + (size_t)(1 + l) * 256, hbuf, (float*)nullptr, N * 32);
  }

  // ---- final linear + BN (no ReLU) -> d_out ----
  hipLaunchKernelGGL((mfma_cat_t<64>), dim3(rowBlocks), dim3(256), 0, stream,
                     (const unsigned short*)nullptr, hbuf, Bpre_all + (size_t)(c0 + L * ch), bl,
                     shadow + (size_t)(1 + L) * shadowN, pre, N, 0, H, 2);
  hipLaunchKernelGGL(bn_coef_k, dim3(1), dim3(128), 0, stream,
                     shadow + (size_t)(1 + L) * shadowN, gl, bel,
                     st + (size_t)(1 + L) * 256, invN);
  hipLaunchKernelGGL((bn_apply_t<0>), dim3(applyBlocks), dim3(256), 0, stream,
                     pre, st + (size_t)(1 + L) * 256, (unsigned short*)nullptr, outp, N * 32);
}